// Round 2
// baseline (491.046 us; speedup 1.0000x reference)
//
#include <hip/hip_runtime.h>
#include <hip/hip_bf16.h>
#include <stdint.h>

// Problem constants: B=4, S=4096, D=1024, H=16, HD=64, LK=256
typedef __bf16 bf16_t;
typedef __attribute__((ext_vector_type(8))) __bf16 bf16x8;
typedef __attribute__((ext_vector_type(4))) __bf16 bf16x4;
typedef __attribute__((ext_vector_type(4))) float f32x4;

#define TO_GLB(p) ((const __attribute__((address_space(1))) void*)(p))
#define TO_LDS(p) ((__attribute__((address_space(3))) void*)(p))

// ---------------- cast fp32 -> bf16, two tensors in one launch ----------------
__global__ __launch_bounds__(256) void cast2_bf16_kernel(const float* __restrict__ a,
                                                         bf16_t* __restrict__ da,
                                                         const float* __restrict__ b,
                                                         bf16_t* __restrict__ db, int n4) {
  int i = blockIdx.x * 256 + threadIdx.x;
  const float* s = (i < n4) ? a : b;
  bf16_t* d = (i < n4) ? da : db;
  int j = (i < n4) ? i : i - n4;
  float4 v = ((const float4*)s)[j];
  bf16x4 o;
  o[0] = (bf16_t)v.x; o[1] = (bf16_t)v.y; o[2] = (bf16_t)v.z; o[3] = (bf16_t)v.w;
  ((bf16x4*)d)[j] = o;
}

// ---------------- transpose-cast 4 square matrices (1024x1024) in one launch ----------------
__global__ __launch_bounds__(256) void transpose_cast4(
    const float* __restrict__ W0, const float* __restrict__ W1, const float* __restrict__ W2,
    const float* __restrict__ W3, bf16_t* __restrict__ o0, bf16_t* __restrict__ o1,
    bf16_t* __restrict__ o2, bf16_t* __restrict__ o3) {
  const int RC = 1024;
  __shared__ bf16_t tile[64][72];
  int z = blockIdx.z;
  const float* W = (z == 0) ? W0 : (z == 1) ? W1 : (z == 2) ? W2 : W3;
  bf16_t* out = (z == 0) ? o0 : (z == 1) ? o1 : (z == 2) ? o2 : o3;
  int r0 = blockIdx.y * 64, c0 = blockIdx.x * 64;
  int tid = threadIdx.x;
#pragma unroll
  for (int p = 0; p < 4; ++p) {
    int r = p * 16 + (tid >> 4);
    int c = (tid & 15) * 4;
    float4 v = *(const float4*)(W + (size_t)(r0 + r) * RC + c0 + c);
    tile[r][c + 0] = (bf16_t)v.x; tile[r][c + 1] = (bf16_t)v.y;
    tile[r][c + 2] = (bf16_t)v.z; tile[r][c + 3] = (bf16_t)v.w;
  }
  __syncthreads();
#pragma unroll
  for (int p = 0; p < 4; ++p) {
    int c = p * 16 + (tid >> 4);
    int r = (tid & 15) * 4;
    bf16x4 o;
    o[0] = tile[r + 0][c]; o[1] = tile[r + 1][c];
    o[2] = tile[r + 2][c]; o[3] = tile[r + 3][c];
    *(bf16x4*)(out + (size_t)(c0 + c) * RC + r0 + r) = o;
  }
}

// ---------------- 256x256xBK64 bf16 GEMM, C = A @ B^T, 8-phase counted-vmcnt ----------------
// 512 threads = 8 waves (2m x 4n). Per-wave output 128x64, acc[8][4].
// LDS: 2 slots x (A 256x64 + B 256x64) bf16 = 128 KiB, 128B rows, xor-swizzled at source.
// Schedule per iteration (2 K-tiles, slot0 phases 1-4, slot1 phases 5-8):
//   each phase stages exactly the half-tile that died at the previous phase's barrier;
//   vmcnt(4) only at phases 4 and 8 (2 half-tiles = 4 loads stay in flight).
// mode 0: QKV projection epilogue; mode 1: output projection epilogue (+bo, fp32)

#define STAGE_A(s, h, k0v)                                                                  \
  do {                                                                                      \
    _Pragma("unroll") for (int it_ = 0; it_ < 2; ++it_) {                                   \
      int brow_ = it_ * 128 + (h) * 64 + (wv << 3);                                         \
      int row_ = brow_ + (lane >> 3);                                                       \
      int cc_ = (lane & 7) ^ (lane >> 3);                                                   \
      const bf16_t* ga_ = Ab + (size_t)row_ * K + (k0v) + cc_ * 8;                          \
      __builtin_amdgcn_global_load_lds(TO_GLB(ga_), TO_LDS(Asl##s + brow_ * 64), 16, 0, 0); \
    }                                                                                       \
  } while (0)

// B stage-half h covers rows {g*64 + h*32 .. +31, g=0..3} (matches n-quadrant deadness)
#define STAGE_B(s, h, k0v)                                                                  \
  do {                                                                                      \
    _Pragma("unroll") for (int it_ = 0; it_ < 2; ++it_) {                                   \
      int brow_ = (it_ * 2 + (wv >> 2)) * 64 + (h) * 32 + ((wv & 3) << 3);                  \
      int row_ = brow_ + (lane >> 3);                                                       \
      int cc_ = (lane & 7) ^ (lane >> 3);                                                   \
      const bf16_t* gb_ = Bb + (size_t)row_ * K + (k0v) + cc_ * 8;                          \
      __builtin_amdgcn_global_load_lds(TO_GLB(gb_), TO_LDS(Bsl##s + brow_ * 64), 16, 0, 0); \
    }                                                                                       \
  } while (0)

#define VM4 asm volatile("s_waitcnt vmcnt(4)" ::: "memory")
#define VMNONE (void)0

#define PHASE(s, mh, nh, STAGE_STMT, VMC)                                                   \
  do {                                                                                      \
    bf16x8 af_[2][4], bf_[2][2];                                                            \
    _Pragma("unroll") for (int kk_ = 0; kk_ < 2; ++kk_) {                                   \
      _Pragma("unroll") for (int t_ = 0; t_ < 4; ++t_) {                                    \
        int ra_ = wm * 128 + (mh) * 64 + t_ * 16 + m_in;                                    \
        af_[kk_][t_] =                                                                      \
            *(const bf16x8*)(Asl##s + ra_ * 64 + (((kk_ * 4 + q) ^ (ra_ & 7)) * 8));        \
      }                                                                                     \
      _Pragma("unroll") for (int n_ = 0; n_ < 2; ++n_) {                                    \
        int rb_ = wn * 64 + (nh) * 32 + n_ * 16 + m_in;                                     \
        bf_[kk_][n_] =                                                                      \
            *(const bf16x8*)(Bsl##s + rb_ * 64 + (((kk_ * 4 + q) ^ (rb_ & 7)) * 8));        \
      }                                                                                     \
    }                                                                                       \
    STAGE_STMT;                                                                             \
    VMC;                                                                                    \
    __builtin_amdgcn_s_barrier();                                                           \
    asm volatile("s_waitcnt lgkmcnt(0)" ::: "memory");                                      \
    __builtin_amdgcn_s_setprio(1);                                                          \
    _Pragma("unroll") for (int kk_ = 0; kk_ < 2; ++kk_)                                     \
        _Pragma("unroll") for (int t_ = 0; t_ < 4; ++t_)                                    \
            _Pragma("unroll") for (int n_ = 0; n_ < 2; ++n_)                                \
                acc[(mh) * 4 + t_][(nh) * 2 + n_] = __builtin_amdgcn_mfma_f32_16x16x32_bf16( \
                    af_[kk_][t_], bf_[kk_][n_], acc[(mh) * 4 + t_][(nh) * 2 + n_], 0, 0, 0); \
    __builtin_amdgcn_s_setprio(0);                                                          \
    __builtin_amdgcn_s_barrier();                                                           \
  } while (0)

__global__ __launch_bounds__(512) void gemm_bt_8ph(
    const bf16_t* __restrict__ A, const bf16_t* __restrict__ B, int K, int mode,
    const float* __restrict__ bq, const float* __restrict__ bk, const float* __restrict__ bv,
    const float* __restrict__ mask,
    bf16_t* __restrict__ Q, bf16_t* __restrict__ KT, bf16_t* __restrict__ VT,
    const float* __restrict__ bo, float* __restrict__ out) {
  int tid = threadIdx.x;
  int lane = tid & 63, wv = tid >> 6;  // 8 waves
  int wm = wv >> 2, wn = wv & 3;       // 2m x 4n
  int q = lane >> 4, m_in = lane & 15;
  int nwg = gridDim.x, cpx = nwg >> 3;
  int bid = blockIdx.x;
  int wgid = (bid & 7) * cpx + (bid >> 3);  // XCD-contiguous chunks (nwg % 8 == 0)
  int bm = wgid & 63, bn = wgid >> 6;       // M blocks always 64 (M=16384)
  size_t m0 = (size_t)bm * 256;
  size_t n0 = (size_t)bn * 256;
  const bf16_t* Ab = A + m0 * K;
  const bf16_t* Bb = B + n0 * K;
  __shared__ __align__(16) bf16_t Asl0[16384];  // 32KB each
  __shared__ __align__(16) bf16_t Asl1[16384];
  __shared__ __align__(16) bf16_t Bsl0[16384];
  __shared__ __align__(16) bf16_t Bsl1[16384];

  f32x4 acc[8][4];
  f32x4 z = {0.f, 0.f, 0.f, 0.f};
#pragma unroll
  for (int mt = 0; mt < 8; ++mt)
#pragma unroll
    for (int nt = 0; nt < 4; ++nt) acc[mt][nt] = z;

  int NT = K >> 6;   // 16 K-tiles
  int NI = NT >> 1;  // 8 iterations, 2 tiles each

  // Prologue: tile0 all 4 halves into slot0; tile1 halves A0,B0 into slot1.
  STAGE_A(0, 0, 0); STAGE_B(0, 0, 0); STAGE_A(0, 1, 0); STAGE_B(0, 1, 0);
  STAGE_A(1, 0, 64); STAGE_B(1, 0, 64);
  asm volatile("s_waitcnt vmcnt(4)" ::: "memory");  // tile0 landed; tile1 A0,B0 in flight
  __builtin_amdgcn_s_barrier();

  for (int i = 0; i < NI; ++i) {
    int kt = 2 * i;
    int k1 = (kt + 1) * 64;
    int k2 = (kt + 2 < NT) ? (kt + 2) * 64 : 0;  // clamped: garbage staged, never read
    int k3 = (kt + 3 < NT) ? (kt + 3) * 64 : 0;
    PHASE(0, 0, 0, STAGE_A(1, 1, k1), VMNONE);  // slot1.A1 dead since prev ph8
    PHASE(0, 0, 1, STAGE_B(1, 1, k1), VMNONE);  // slot1.B1 dead since prev ph8
    PHASE(0, 1, 0, STAGE_A(0, 0, k2), VMNONE);  // slot0.A0 dead after ph2
    PHASE(0, 1, 1, STAGE_B(0, 0, k2), VM4);     // slot0.B0 dead after ph3; drain tile kt+1
    PHASE(1, 0, 0, STAGE_A(0, 1, k2), VMNONE);  // slot0.A1 dead after ph4
    PHASE(1, 0, 1, STAGE_B(0, 1, k2), VMNONE);  // slot0.B1 dead after ph4
    PHASE(1, 1, 0, STAGE_A(1, 0, k3), VMNONE);  // slot1.A0 dead after ph6
    PHASE(1, 1, 1, STAGE_B(1, 0, k3), VM4);     // slot1.B0 dead after ph7; drain tile kt+2
  }
  // Drain trailing garbage prefetches: a retiring WG's in-flight global_load_lds
  // would otherwise land in a newly-dispatched WG's LDS on the same CU.
  asm volatile("s_waitcnt vmcnt(0)" ::: "memory");

  if (mode == 0) {
#pragma unroll
    for (int mt = 0; mt < 8; ++mt) {
      int mbase = (int)m0 + wm * 128 + mt * 16 + q * 4;  // token index, %4==0
      int b = mbase >> 12, s = mbase & 4095;
      float mk[4];
#pragma unroll
      for (int r = 0; r < 4; ++r) mk[r] = mask[b * 4096 + s + r];
#pragma unroll
      for (int nt = 0; nt < 4; ++nt) {
        int nG = (int)n0 + wn * 64 + nt * 16 + m_in;
        int proj = nG >> 10, c = nG & 1023, h = c >> 6, hd = c & 63;
        const float* bp = (proj == 0) ? bq : ((proj == 1) ? bk : bv);
        float bias = bp[c];
        if (proj == 0) {
#pragma unroll
          for (int r = 0; r < 4; ++r)
            Q[((size_t)(b * 16 + h) * 4096 + s + r) * 64 + hd] = (bf16_t)(acc[mt][nt][r] + bias);
        } else {
          bf16_t* dst = (proj == 1) ? KT : VT;
          bf16x4 v;
#pragma unroll
          for (int r = 0; r < 4; ++r) v[r] = (bf16_t)((acc[mt][nt][r] + bias) * mk[r]);
          *(bf16x4*)(dst + ((size_t)(b * 16 + h) * 64 + hd) * 4096 + s) = v;
        }
      }
    }
  } else {
#pragma unroll
    for (int mt = 0; mt < 8; ++mt) {
      int t = (int)m0 + wm * 128 + mt * 16 + q * 4;
#pragma unroll
      for (int nt = 0; nt < 4; ++nt) {
        int nG = (int)n0 + wn * 64 + nt * 16 + m_in;
        float bias = bo[nG];
#pragma unroll
        for (int r = 0; r < 4; ++r) out[(size_t)(t + r) * 1024 + nG] = acc[mt][nt][r] + bias;
      }
    }
  }
}

// ---------------- GEMM2 split-K: partial = E_h @ (masked K/V chunk)^T ----------------
// Grid (2 mt, 64 bh, 8 = kv*4+kc), 512 threads, BK=128.
// LDS [kkblk(2)][row][64]: 128B rows, xor-swizzled (same scheme as gemm_bt).
__global__ __launch_bounds__(512) void gemm2_kernel(
    const bf16_t* __restrict__ E, const bf16_t* __restrict__ KT, const bf16_t* __restrict__ VT,
    float* __restrict__ Pp) {
  int tid = threadIdx.x, lane = tid & 63, wv = tid >> 6;  // 8 waves
  int wm = wv >> 1, wn = wv & 1;
  int q = lane >> 4, m_in = lane & 15;
  int mt0 = blockIdx.x;
  int bh = blockIdx.y;
  int kv = blockIdx.z >> 2, kc = blockIdx.z & 3;
  int h = bh & 15;
  const bf16_t* Ab = E + (size_t)h * 256 * 4096 + (size_t)mt0 * 128 * 4096 + kc * 1024;
  const bf16_t* Bb = (kv ? VT : KT) + (size_t)bh * 64 * 4096 + kc * 1024;
  __shared__ __align__(16) bf16_t As[2 * 128 * 64];  // 32KB, [kkblk][row][64]
  __shared__ __align__(16) bf16_t Bs[2 * 64 * 64];   // 16KB, [kkblk][row][64]

  f32x4 acc[2][2];
  f32x4 z = {0.f, 0.f, 0.f, 0.f};
#pragma unroll
  for (int mt = 0; mt < 2; ++mt)
#pragma unroll
    for (int nt = 0; nt < 2; ++nt) acc[mt][nt] = z;

  for (int k0 = 0; k0 < 1024; k0 += 128) {
#pragma unroll
    for (int it = 0; it < 4; ++it) {  // As: 2048 chunks of 16B
      int l = it * 512 + tid;
      int kkb = l >> 10, row = (l >> 3) & 127, cc = (l & 7) ^ (row & 7);
      const bf16_t* ga = Ab + (size_t)row * 4096 + k0 + kkb * 64 + cc * 8;
      __builtin_amdgcn_global_load_lds(TO_GLB(ga), TO_LDS(As + (it * 512 + wv * 64) * 8), 16, 0, 0);
    }
#pragma unroll
    for (int it = 0; it < 2; ++it) {  // Bs: 1024 chunks
      int l = it * 512 + tid;
      int kkb = l >> 9, row = (l >> 3) & 63, cc = (l & 7) ^ (row & 7);
      const bf16_t* gb = Bb + (size_t)row * 4096 + k0 + kkb * 64 + cc * 8;
      __builtin_amdgcn_global_load_lds(TO_GLB(gb), TO_LDS(Bs + (it * 512 + wv * 64) * 8), 16, 0, 0);
    }
    __syncthreads();
#pragma unroll
    for (int kk4 = 0; kk4 < 4; ++kk4) {
      int kkb = kk4 >> 1, qq = (kk4 & 1) * 4 + q;
      bf16x8 af[2], bfr[2];
#pragma unroll
      for (int mt = 0; mt < 2; ++mt) {
        int ra = wm * 32 + mt * 16 + m_in;
        af[mt] = *(const bf16x8*)(As + kkb * 8192 + ra * 64 + ((qq ^ (ra & 7)) * 8));
      }
#pragma unroll
      for (int nt = 0; nt < 2; ++nt) {
        int rb = wn * 32 + nt * 16 + m_in;
        bfr[nt] = *(const bf16x8*)(Bs + kkb * 4096 + rb * 64 + ((qq ^ (rb & 7)) * 8));
      }
#pragma unroll
      for (int mt = 0; mt < 2; ++mt)
#pragma unroll
        for (int nt = 0; nt < 2; ++nt)
          acc[mt][nt] = __builtin_amdgcn_mfma_f32_16x16x32_bf16(af[mt], bfr[nt], acc[mt][nt], 0, 0, 0);
    }
    __syncthreads();
  }

  float* P = Pp + ((size_t)(bh * 2 + kv) * 4 + kc) * 16384;
#pragma unroll
  for (int mt = 0; mt < 2; ++mt) {
    int lk = mt0 * 128 + wm * 32 + mt * 16 + q * 4;
#pragma unroll
    for (int nt = 0; nt < 2; ++nt) {
      int hd = wn * 32 + nt * 16 + m_in;
#pragma unroll
      for (int r = 0; r < 4; ++r) P[(size_t)(lk + r) * 64 + hd] = acc[mt][nt][r];
    }
  }
}

// ---------------- reduce 4 split-K partials -> Kp bf16 [lk][hd], VpT bf16 [hd][lk] ----------------
__global__ __launch_bounds__(256) void gemm2_reduce(const float* __restrict__ Pp,
                                                    bf16_t* __restrict__ Kp,
                                                    bf16_t* __restrict__ VpT) {
  int bh = blockIdx.x, kv = blockIdx.y;
  int tid = threadIdx.x;
  const float* P = Pp + ((size_t)(bh * 2 + kv) * 4) * 16384;
#pragma unroll
  for (int it = 0; it < 16; ++it) {
    int e4 = it * 256 + tid;  // f32x4 index within 16384
    f32x4 s = *(const f32x4*)(P + e4 * 4);
    f32x4 s1 = *(const f32x4*)(P + 16384 + e4 * 4);
    f32x4 s2 = *(const f32x4*)(P + 32768 + e4 * 4);
    f32x4 s3 = *(const f32x4*)(P + 49152 + e4 * 4);
    s += s1; s += s2; s += s3;
    if (kv == 0) {
      bf16x4 v;
#pragma unroll
      for (int r = 0; r < 4; ++r) v[r] = (bf16_t)s[r];
      *(bf16x4*)(Kp + (size_t)bh * 16384 + e4 * 4) = v;
    } else {
      int lk = (e4 * 4) >> 6, hd = (e4 * 4) & 63;
      bf16_t* d = VpT + (size_t)bh * 16384 + lk;
#pragma unroll
      for (int r = 0; r < 4; ++r) d[(size_t)(hd + r) * 256] = (bf16_t)s[r];
    }
  }
}

// ---------------- fused attention: scores -> softmax -> PV ----------------
// Grid (S/64, B*H), 256 threads (4 waves x 16 Q-rows each).
// LDS reused 3x: Kp ([256][64] 128B-row swizzled) -> P (xor) -> Vp ([64][256] swizzled).
__global__ __launch_bounds__(256) void attn_kernel(
    const bf16_t* __restrict__ Q, const bf16_t* __restrict__ Kp, const bf16_t* __restrict__ VpT,
    bf16_t* __restrict__ Xo) {
  int tid = threadIdx.x, lane = tid & 63, wv = tid >> 6;
  int q = lane >> 4, m_in = lane & 15;
  int s0 = blockIdx.x * 64;
  int bh = blockIdx.y;
  int b = bh >> 4, h = bh & 15;
  const bf16_t* Qb = Q + ((size_t)bh * 4096 + s0 + wv * 16) * 64;
  const bf16_t* Kpb = Kp + (size_t)bh * 16384;
  const bf16_t* Vb = VpT + (size_t)bh * 16384;
  __shared__ __align__(16) bf16_t buf[16384];  // 32KB, reused Kp -> P -> Vp

  // stage Kp [256][64]: 128B rows, chunk cc holds source chunk cc^(row&7)
#pragma unroll
  for (int it = 0; it < 8; ++it) {
    int l = it * 256 + tid;
    int row = l >> 3, cc = (l & 7) ^ (row & 7);
    const bf16_t* g = Kpb + row * 64 + cc * 8;
    __builtin_amdgcn_global_load_lds(TO_GLB(g), TO_LDS(buf + (it * 256 + wv * 64) * 8), 16, 0, 0);
  }
  bf16x8 aq[2];
#pragma unroll
  for (int ks = 0; ks < 2; ++ks) aq[ks] = *(const bf16x8*)(Qb + (size_t)m_in * 64 + ks * 32 + q * 8);
  __syncthreads();  // B0: Kp staged

  f32x4 sc[16];
  f32x4 z = {0.f, 0.f, 0.f, 0.f};
#pragma unroll
  for (int nt = 0; nt < 16; ++nt) sc[nt] = z;
#pragma unroll
  for (int nt = 0; nt < 16; ++nt)
#pragma unroll
    for (int ks = 0; ks < 2; ++ks) {
      int nb = nt * 16 + m_in, qq = ks * 4 + q;
      bf16x8 kb = *(const bf16x8*)(buf + nb * 64 + ((qq ^ (nb & 7)) * 8));
      sc[nt] = __builtin_amdgcn_mfma_f32_16x16x32_bf16(aq[ks], kb, sc[nt], 0, 0, 0);
    }

  float mx[4], sm[4];
#pragma unroll
  for (int r = 0; r < 4; ++r) mx[r] = -1e30f;
#pragma unroll
  for (int nt = 0; nt < 16; ++nt)
#pragma unroll
    for (int r = 0; r < 4; ++r) {
      float t = sc[nt][r] * 0.125f;  // 1/sqrt(HD)
      sc[nt][r] = t;
      mx[r] = fmaxf(mx[r], t);
    }
#pragma unroll
  for (int off = 1; off < 16; off <<= 1)
#pragma unroll
    for (int r = 0; r < 4; ++r) mx[r] = fmaxf(mx[r], __shfl_xor(mx[r], off));
#pragma unroll
  for (int r = 0; r < 4; ++r) sm[r] = 0.f;
#pragma unroll
  for (int nt = 0; nt < 16; ++nt)
#pragma unroll
    for (int r = 0; r < 4; ++r) {
      float e = __expf(sc[nt][r] - mx[r]);
      sc[nt][r] = e;
      sm[r] += e;
    }
#pragma unroll
  for (int off = 1; off < 16; off <<= 1)
#pragma unroll
    for (int r = 0; r < 4; ++r) sm[r] += __shfl_xor(sm[r], off);
  float inv[4];
#pragma unroll
  for (int r = 0; r < 4; ++r) inv[r] = 1.0f / sm[r];

  __syncthreads();  // B1: all waves done reading Kp

  bf16_t* Pw = buf + wv * 4096;
#pragma unroll
  for (int nt = 0; nt < 16; ++nt) {
    int cw = nt * 2 + (m_in >> 3);
#pragma unroll
    for (int r = 0; r < 4; ++r) {
      int rp = q * 4 + r;
      int sw = (((cw ^ (rp & 7)) << 3) | (m_in & 7));
      Pw[rp * 256 + sw] = (bf16_t)(sc[nt][r] * inv[r]);
    }
  }
  bf16x8 pa[8];
#pragma unroll
  for (int ks = 0; ks < 8; ++ks) {
    int c = ks * 4 + q;
    pa[ks] = *(const bf16x8*)(Pw + m_in * 256 + ((c ^ (m_in & 7)) << 3));
  }
  __syncthreads();  // B2: all waves hold pa

  // stage Vp [64][256]: 512B rows; position cc holds source chunk with low3 ^= row&7
#pragma unroll
  for (int it = 0; it < 8; ++it) {
    int l = it * 256 + tid;
    int row = l >> 5, cc = l & 31;
    int src_cc = (cc & 24) | ((cc ^ row) & 7);
    const bf16_t* g = Vb + row * 256 + src_cc * 8;
    __builtin_amdgcn_global_load_lds(TO_GLB(g), TO_LDS(buf + (it * 256 + wv * 64) * 8), 16, 0, 0);
  }
  __syncthreads();  // B3: Vp staged

  f32x4 o[4];
#pragma unroll
  for (int nt = 0; nt < 4; ++nt) o[nt] = z;
#pragma unroll
  for (int nt = 0; nt < 4; ++nt)
#pragma unroll
    for (int ks = 0; ks < 8; ++ks) {
      int nb = nt * 16 + m_in, qq = ks * 4 + q;
      int p = (qq & 24) | ((qq ^ nb) & 7);
      bf16x8 vb = *(const bf16x8*)(buf + nb * 256 + p * 8);
      o[nt] = __builtin_amdgcn_mfma_f32_16x16x32_bf16(pa[ks], vb, o[nt], 0, 0, 0);
    }

#pragma unroll
  for (int nt = 0; nt < 4; ++nt)
#pragma unroll
    for (int r = 0; r < 4; ++r)
      Xo[((size_t)b * 4096 + s0 + wv * 16 + q * 4 + r) * 1024 + h * 64 + nt * 16 + m_in] =
          (bf16_t)o[nt][r];
}

extern "C" void kernel_launch(void* const* d_in, const int* in_sizes, int n_in,
                              void* d_out, int out_size, void* d_ws, size_t ws_size,
                              hipStream_t stream) {
  const float* X = (const float*)d_in[0];
  const float* mask = (const float*)d_in[1];
  const float* Wq = (const float*)d_in[2];
  const float* bq = (const float*)d_in[3];
  const float* Wk = (const float*)d_in[4];
  const float* bk = (const float*)d_in[5];
  const float* Wv = (const float*)d_in[6];
  const float* bv = (const float*)d_in[7];
  const float* E = (const float*)d_in[8];
  const float* Wo = (const float*)d_in[9];
  const float* bo = (const float*)d_in[10];
  float* out = (float*)d_out;

  char* ws = (char*)d_ws;
  const size_t SZ = 33554432;  // 32 MB
  bf16_t* Xb = (bf16_t*)(ws);                 // Xb -> gemm2 partials (fp32) -> Xo
  float* Pp = (float*)(ws);                   // 32 MB fp32 partials (alias, Xb dead then)
  bf16_t* Eb = (bf16_t*)(ws + SZ);
  bf16_t* Qb = (bf16_t*)(ws + 2 * SZ);
  bf16_t* KT = (bf16_t*)(ws + 3 * SZ);        // (B,H,HD,S) masked
  bf16_t* VT = (bf16_t*)(ws + 4 * SZ);        // (B,H,HD,S) masked
  bf16_t* Kp = (bf16_t*)(ws + 5 * SZ);                 // (B,H,LK,HD)
  bf16_t* VpT = (bf16_t*)(ws + 5 * SZ + 8388608);      // (B,H,HD,LK)
  bf16_t* WqkvT = (bf16_t*)(ws + 5 * SZ + 2 * 8388608);           // (3072,1024)
  bf16_t* WoT = (bf16_t*)(ws + 5 * SZ + 2 * 8388608 + 6291456);   // (1024,1024)
  bf16_t* Xo = Xb;

  cast2_bf16_kernel<<<32768, 256, 0, stream>>>(X, Xb, E, Eb, 4194304);
  transpose_cast4<<<dim3(16, 16, 4), 256, 0, stream>>>(
      Wq, Wk, Wv, Wo, WqkvT, WqkvT + 1048576, WqkvT + 2097152, WoT);

  // QKV projection: M=16384, N=3072 -> 64 x 12 = 768 blocks (%8==0 for XCD swizzle)
  gemm_bt_8ph<<<768, 512, 0, stream>>>(Xb, WqkvT, 1024, 0, bq, bk, bv, mask,
                                       Qb, KT, VT, nullptr, nullptr);
  gemm2_kernel<<<dim3(2, 64, 8), 512, 0, stream>>>(Eb, KT, VT, Pp);
  gemm2_reduce<<<dim3(64, 2), 256, 0, stream>>>(Pp, Kp, VpT);
  attn_kernel<<<dim3(64, 64), 256, 0, stream>>>(Qb, Kp, VpT, Xo);
  // Output projection: M=16384, N=1024 -> 64 x 4 = 256 blocks
  gemm_bt_8ph<<<256, 512, 0, stream>>>(Xo, WoT, 1024, 1, nullptr, nullptr, nullptr,
                                       nullptr, nullptr, nullptr, nullptr, bo, out);
}

// Round 3
// 473.071 us; speedup vs baseline: 1.0380x; 1.0380x over previous
//
#include <hip/hip_runtime.h>
#include <hip/hip_bf16.h>
#include <stdint.h>

// Problem constants: B=4, S=4096, D=1024, H=16, HD=64, LK=256
typedef __bf16 bf16_t;
typedef __attribute__((ext_vector_type(8))) __bf16 bf16x8;
typedef __attribute__((ext_vector_type(4))) __bf16 bf16x4;
typedef __attribute__((ext_vector_type(4))) float f32x4;

#define TO_GLB(p) ((const __attribute__((address_space(1))) void*)(p))
#define TO_LDS(p) ((__attribute__((address_space(3))) void*)(p))

// ---------------- cast fp32 -> bf16, two tensors in one launch ----------------
__global__ __launch_bounds__(256) void cast2_bf16_kernel(const float* __restrict__ a,
                                                         bf16_t* __restrict__ da,
                                                         const float* __restrict__ b,
                                                         bf16_t* __restrict__ db, int n4) {
  int i = blockIdx.x * 256 + threadIdx.x;
  const float* s = (i < n4) ? a : b;
  bf16_t* d = (i < n4) ? da : db;
  int j = (i < n4) ? i : i - n4;
  float4 v = ((const float4*)s)[j];
  bf16x4 o;
  o[0] = (bf16_t)v.x; o[1] = (bf16_t)v.y; o[2] = (bf16_t)v.z; o[3] = (bf16_t)v.w;
  ((bf16x4*)d)[j] = o;
}

// ---------------- transpose-cast 4 square matrices (1024x1024) in one launch ----------------
__global__ __launch_bounds__(256) void transpose_cast4(
    const float* __restrict__ W0, const float* __restrict__ W1, const float* __restrict__ W2,
    const float* __restrict__ W3, bf16_t* __restrict__ o0, bf16_t* __restrict__ o1,
    bf16_t* __restrict__ o2, bf16_t* __restrict__ o3) {
  const int RC = 1024;
  __shared__ bf16_t tile[64][72];
  int z = blockIdx.z;
  const float* W = (z == 0) ? W0 : (z == 1) ? W1 : (z == 2) ? W2 : W3;
  bf16_t* out = (z == 0) ? o0 : (z == 1) ? o1 : (z == 2) ? o2 : o3;
  int r0 = blockIdx.y * 64, c0 = blockIdx.x * 64;
  int tid = threadIdx.x;
#pragma unroll
  for (int p = 0; p < 4; ++p) {
    int r = p * 16 + (tid >> 4);
    int c = (tid & 15) * 4;
    float4 v = *(const float4*)(W + (size_t)(r0 + r) * RC + c0 + c);
    tile[r][c + 0] = (bf16_t)v.x; tile[r][c + 1] = (bf16_t)v.y;
    tile[r][c + 2] = (bf16_t)v.z; tile[r][c + 3] = (bf16_t)v.w;
  }
  __syncthreads();
#pragma unroll
  for (int p = 0; p < 4; ++p) {
    int c = p * 16 + (tid >> 4);
    int r = (tid & 15) * 4;
    bf16x4 o;
    o[0] = tile[r + 0][c]; o[1] = tile[r + 1][c];
    o[2] = tile[r + 2][c]; o[3] = tile[r + 3][c];
    *(bf16x4*)(out + (size_t)(c0 + c) * RC + r0 + r) = o;
  }
}

// ---------------- 256x256xBK64 bf16 GEMM, C = A @ B^T, 8-phase counted-vmcnt ----------------
// 512 threads = 8 waves (2m x 4n). Per-wave output 128x64, acc[8][4].
// LDS: 2 slots x (A 256x64 + B 256x64) bf16 = 128 KiB, 128B rows, xor-swizzled at source.
// Register-held fragments: af loaded once per m-half (reused across both n-phases),
// bf0/bf1 loaded once per K-tile (reused across both m-halves) -> 24 ds_read_b128
// per K-tile per wave (vs 48 redundant), keeping LDS below the MFMA critical path.
// vmcnt(4) only at K-tile boundaries (2 half-tiles = 4 loads stay in flight).
// No XCD swizzle: plain x-fastest order gives each XCD bm = xcd (mod 8) -> 4MB
// A working set resident in its L2 across the bn sweep (round-0-proven locality).

#define STAGE_A(s, h, k0v)                                                                  \
  do {                                                                                      \
    _Pragma("unroll") for (int it_ = 0; it_ < 2; ++it_) {                                   \
      int brow_ = it_ * 128 + (h) * 64 + (wv << 3);                                         \
      int row_ = brow_ + (lane >> 3);                                                       \
      int cc_ = (lane & 7) ^ (lane >> 3);                                                   \
      const bf16_t* ga_ = Ab + (size_t)row_ * K + (k0v) + cc_ * 8;                          \
      __builtin_amdgcn_global_load_lds(TO_GLB(ga_), TO_LDS(Asl##s + brow_ * 64), 16, 0, 0); \
    }                                                                                       \
  } while (0)

// B stage-half h covers rows {g*64 + h*32 .. +31, g=0..3} (matches n-quadrant deadness)
#define STAGE_B(s, h, k0v)                                                                  \
  do {                                                                                      \
    _Pragma("unroll") for (int it_ = 0; it_ < 2; ++it_) {                                   \
      int brow_ = (it_ * 2 + (wv >> 2)) * 64 + (h) * 32 + ((wv & 3) << 3);                  \
      int row_ = brow_ + (lane >> 3);                                                       \
      int cc_ = (lane & 7) ^ (lane >> 3);                                                   \
      const bf16_t* gb_ = Bb + (size_t)row_ * K + (k0v) + cc_ * 8;                          \
      __builtin_amdgcn_global_load_lds(TO_GLB(gb_), TO_LDS(Bsl##s + brow_ * 64), 16, 0, 0); \
    }                                                                                       \
  } while (0)

#define VM4 asm volatile("s_waitcnt vmcnt(4)" ::: "memory")
#define BARRIER __builtin_amdgcn_s_barrier()
#define LGKM0 asm volatile("s_waitcnt lgkmcnt(0)" ::: "memory")

#define LOAD_AF(s, mh)                                                                      \
  do {                                                                                      \
    _Pragma("unroll") for (int kk_ = 0; kk_ < 2; ++kk_)                                     \
        _Pragma("unroll") for (int t_ = 0; t_ < 4; ++t_) {                                  \
      int ra_ = wm * 128 + (mh) * 64 + t_ * 16 + m_in;                                      \
      af[kk_][t_] = *(const bf16x8*)(Asl##s + ra_ * 64 + (((kk_ * 4 + q) ^ (ra_ & 7)) * 8)); \
    }                                                                                       \
  } while (0)

#define LOAD_BF(s, nh, dst)                                                                 \
  do {                                                                                      \
    _Pragma("unroll") for (int kk_ = 0; kk_ < 2; ++kk_)                                     \
        _Pragma("unroll") for (int n_ = 0; n_ < 2; ++n_) {                                  \
      int rb_ = wn * 64 + (nh) * 32 + n_ * 16 + m_in;                                       \
      dst[kk_][n_] = *(const bf16x8*)(Bsl##s + rb_ * 64 + (((kk_ * 4 + q) ^ (rb_ & 7)) * 8)); \
    }                                                                                       \
  } while (0)

#define MFMA_Q(mh, nh, bfr)                                                                 \
  do {                                                                                      \
    __builtin_amdgcn_s_setprio(1);                                                          \
    _Pragma("unroll") for (int kk_ = 0; kk_ < 2; ++kk_)                                     \
        _Pragma("unroll") for (int t_ = 0; t_ < 4; ++t_)                                    \
            _Pragma("unroll") for (int n_ = 0; n_ < 2; ++n_)                                \
                acc[(mh) * 4 + t_][(nh) * 2 + n_] = __builtin_amdgcn_mfma_f32_16x16x32_bf16( \
                    af[kk_][t_], bfr[kk_][n_], acc[(mh) * 4 + t_][(nh) * 2 + n_], 0, 0, 0);  \
    __builtin_amdgcn_s_setprio(0);                                                          \
  } while (0)

// One K-tile = 4 phases. ds_reads per phase: 12 / 4 / 8 / 0.
#define KTILE(s, ST1, ST2, ST3, ST4)                                                        \
  do {                                                                                      \
    LOAD_AF(s, 0); LOAD_BF(s, 0, bf0);                                                      \
    ST1; BARRIER; LGKM0; MFMA_Q(0, 0, bf0); BARRIER;                                        \
    LOAD_BF(s, 1, bf1);                                                                     \
    ST2; BARRIER; LGKM0; MFMA_Q(0, 1, bf1); BARRIER;                                        \
    LOAD_AF(s, 1);                                                                          \
    ST3; BARRIER; LGKM0; MFMA_Q(1, 0, bf0); BARRIER;                                        \
    ST4; VM4; BARRIER; MFMA_Q(1, 1, bf1); BARRIER;                                          \
  } while (0)

__global__ __launch_bounds__(512, 2) void gemm_bt_8ph(
    const bf16_t* __restrict__ A, const bf16_t* __restrict__ B, int K, int mode,
    const float* __restrict__ bq, const float* __restrict__ bk, const float* __restrict__ bv,
    const float* __restrict__ mask,
    bf16_t* __restrict__ Q, bf16_t* __restrict__ KT, bf16_t* __restrict__ VT,
    const float* __restrict__ bo, float* __restrict__ out) {
  int tid = threadIdx.x;
  int lane = tid & 63, wv = tid >> 6;  // 8 waves
  int wm = wv >> 2, wn = wv & 3;       // 2m x 4n
  int q = lane >> 4, m_in = lane & 15;
  int bid = blockIdx.x;
  int bm = bid & 63, bn = bid >> 6;  // x-fastest: XCD c holds bm == c (mod 8), L2-stable
  size_t m0 = (size_t)bm * 256;
  size_t n0 = (size_t)bn * 256;
  const bf16_t* Ab = A + m0 * K;
  const bf16_t* Bb = B + n0 * K;
  __shared__ __align__(16) bf16_t Asl0[16384];  // 32KB each
  __shared__ __align__(16) bf16_t Asl1[16384];
  __shared__ __align__(16) bf16_t Bsl0[16384];
  __shared__ __align__(16) bf16_t Bsl1[16384];

  f32x4 acc[8][4];
  bf16x8 af[2][4], bf0[2][2], bf1[2][2];
  f32x4 z = {0.f, 0.f, 0.f, 0.f};
#pragma unroll
  for (int mt = 0; mt < 8; ++mt)
#pragma unroll
    for (int nt = 0; nt < 4; ++nt) acc[mt][nt] = z;

  int NT = K >> 6;   // 16 K-tiles
  int NI = NT >> 1;  // 8 iterations, 2 tiles each

  // Prologue: tile0 all 4 halves into slot0; tile1 halves A0,B0 into slot1.
  STAGE_A(0, 0, 0); STAGE_B(0, 0, 0); STAGE_A(0, 1, 0); STAGE_B(0, 1, 0);
  STAGE_A(1, 0, 64); STAGE_B(1, 0, 64);
  asm volatile("s_waitcnt vmcnt(4)" ::: "memory");  // tile0 landed; tile1 A0,B0 in flight
  __builtin_amdgcn_s_barrier();

  for (int i = 0; i < NI; ++i) {
    int kt = 2 * i;
    int k1 = (kt + 1) * 64;
    int k2 = (kt + 2 < NT) ? (kt + 2) * 64 : 0;  // clamped: garbage staged, never read
    int k3 = (kt + 3 < NT) ? (kt + 3) * 64 : 0;
    KTILE(0, STAGE_A(1, 1, k1), STAGE_B(1, 1, k1), STAGE_A(0, 0, k2), STAGE_B(0, 0, k2));
    KTILE(1, STAGE_A(0, 1, k2), STAGE_B(0, 1, k2), STAGE_A(1, 0, k3), STAGE_B(1, 0, k3));
  }
  // Drain trailing garbage prefetches: a retiring WG's in-flight global_load_lds
  // would otherwise land in a newly-dispatched WG's LDS on the same CU.
  asm volatile("s_waitcnt vmcnt(0)" ::: "memory");

  if (mode == 0) {
#pragma unroll
    for (int mt = 0; mt < 8; ++mt) {
      int mbase = (int)m0 + wm * 128 + mt * 16 + q * 4;  // token index, %4==0
      int b = mbase >> 12, s = mbase & 4095;
      float mk[4];
#pragma unroll
      for (int r = 0; r < 4; ++r) mk[r] = mask[b * 4096 + s + r];
#pragma unroll
      for (int nt = 0; nt < 4; ++nt) {
        int nG = (int)n0 + wn * 64 + nt * 16 + m_in;
        int proj = nG >> 10, c = nG & 1023, h = c >> 6, hd = c & 63;
        const float* bp = (proj == 0) ? bq : ((proj == 1) ? bk : bv);
        float bias = bp[c];
        if (proj == 0) {
#pragma unroll
          for (int r = 0; r < 4; ++r)
            Q[((size_t)(b * 16 + h) * 4096 + s + r) * 64 + hd] = (bf16_t)(acc[mt][nt][r] + bias);
        } else {
          bf16_t* dst = (proj == 1) ? KT : VT;
          bf16x4 v;
#pragma unroll
          for (int r = 0; r < 4; ++r) v[r] = (bf16_t)((acc[mt][nt][r] + bias) * mk[r]);
          *(bf16x4*)(dst + ((size_t)(b * 16 + h) * 64 + hd) * 4096 + s) = v;
        }
      }
    }
  } else {
#pragma unroll
    for (int mt = 0; mt < 8; ++mt) {
      int t = (int)m0 + wm * 128 + mt * 16 + q * 4;
#pragma unroll
      for (int nt = 0; nt < 4; ++nt) {
        int nG = (int)n0 + wn * 64 + nt * 16 + m_in;
        float bias = bo[nG];
#pragma unroll
        for (int r = 0; r < 4; ++r) out[(size_t)(t + r) * 1024 + nG] = acc[mt][nt][r] + bias;
      }
    }
  }
}

// ---------------- GEMM2 split-K: partial = E_h @ (masked K/V chunk)^T ----------------
// Grid (2 mt, 64 bh, 8 = kv*4+kc), 512 threads, BK=128.
// LDS [kkblk(2)][row][64]: 128B rows, xor-swizzled (same scheme as gemm_bt).
__global__ __launch_bounds__(512) void gemm2_kernel(
    const bf16_t* __restrict__ E, const bf16_t* __restrict__ KT, const bf16_t* __restrict__ VT,
    float* __restrict__ Pp) {
  int tid = threadIdx.x, lane = tid & 63, wv = tid >> 6;  // 8 waves
  int wm = wv >> 1, wn = wv & 1;
  int q = lane >> 4, m_in = lane & 15;
  int mt0 = blockIdx.x;
  int bh = blockIdx.y;
  int kv = blockIdx.z >> 2, kc = blockIdx.z & 3;
  int h = bh & 15;
  const bf16_t* Ab = E + (size_t)h * 256 * 4096 + (size_t)mt0 * 128 * 4096 + kc * 1024;
  const bf16_t* Bb = (kv ? VT : KT) + (size_t)bh * 64 * 4096 + kc * 1024;
  __shared__ __align__(16) bf16_t As[2 * 128 * 64];  // 32KB, [kkblk][row][64]
  __shared__ __align__(16) bf16_t Bs[2 * 64 * 64];   // 16KB, [kkblk][row][64]

  f32x4 acc[2][2];
  f32x4 z = {0.f, 0.f, 0.f, 0.f};
#pragma unroll
  for (int mt = 0; mt < 2; ++mt)
#pragma unroll
    for (int nt = 0; nt < 2; ++nt) acc[mt][nt] = z;

  for (int k0 = 0; k0 < 1024; k0 += 128) {
#pragma unroll
    for (int it = 0; it < 4; ++it) {  // As: 2048 chunks of 16B
      int l = it * 512 + tid;
      int kkb = l >> 10, row = (l >> 3) & 127, cc = (l & 7) ^ (row & 7);
      const bf16_t* ga = Ab + (size_t)row * 4096 + k0 + kkb * 64 + cc * 8;
      __builtin_amdgcn_global_load_lds(TO_GLB(ga), TO_LDS(As + (it * 512 + wv * 64) * 8), 16, 0, 0);
    }
#pragma unroll
    for (int it = 0; it < 2; ++it) {  // Bs: 1024 chunks
      int l = it * 512 + tid;
      int kkb = l >> 9, row = (l >> 3) & 63, cc = (l & 7) ^ (row & 7);
      const bf16_t* gb = Bb + (size_t)row * 4096 + k0 + kkb * 64 + cc * 8;
      __builtin_amdgcn_global_load_lds(TO_GLB(gb), TO_LDS(Bs + (it * 512 + wv * 64) * 8), 16, 0, 0);
    }
    __syncthreads();
#pragma unroll
    for (int kk4 = 0; kk4 < 4; ++kk4) {
      int kkb = kk4 >> 1, qq = (kk4 & 1) * 4 + q;
      bf16x8 af[2], bfr[2];
#pragma unroll
      for (int mt = 0; mt < 2; ++mt) {
        int ra = wm * 32 + mt * 16 + m_in;
        af[mt] = *(const bf16x8*)(As + kkb * 8192 + ra * 64 + ((qq ^ (ra & 7)) * 8));
      }
#pragma unroll
      for (int nt = 0; nt < 2; ++nt) {
        int rb = wn * 32 + nt * 16 + m_in;
        bfr[nt] = *(const bf16x8*)(Bs + kkb * 4096 + rb * 64 + ((qq ^ (rb & 7)) * 8));
      }
#pragma unroll
      for (int mt = 0; mt < 2; ++mt)
#pragma unroll
        for (int nt = 0; nt < 2; ++nt)
          acc[mt][nt] = __builtin_amdgcn_mfma_f32_16x16x32_bf16(af[mt], bfr[nt], acc[mt][nt], 0, 0, 0);
    }
    __syncthreads();
  }

  float* P = Pp + ((size_t)(bh * 2 + kv) * 4 + kc) * 16384;
#pragma unroll
  for (int mt = 0; mt < 2; ++mt) {
    int lk = mt0 * 128 + wm * 32 + mt * 16 + q * 4;
#pragma unroll
    for (int nt = 0; nt < 2; ++nt) {
      int hd = wn * 32 + nt * 16 + m_in;
#pragma unroll
      for (int r = 0; r < 4; ++r) P[(size_t)(lk + r) * 64 + hd] = acc[mt][nt][r];
    }
  }
}

// ---------------- reduce 4 split-K partials -> Kp bf16 [lk][hd], VpT bf16 [hd][lk] ----------------
__global__ __launch_bounds__(256) void gemm2_reduce(const float* __restrict__ Pp,
                                                    bf16_t* __restrict__ Kp,
                                                    bf16_t* __restrict__ VpT) {
  int bh = blockIdx.x, kv = blockIdx.y;
  int tid = threadIdx.x;
  const float* P = Pp + ((size_t)(bh * 2 + kv) * 4) * 16384;
#pragma unroll
  for (int it = 0; it < 16; ++it) {
    int e4 = it * 256 + tid;  // f32x4 index within 16384
    f32x4 s = *(const f32x4*)(P + e4 * 4);
    f32x4 s1 = *(const f32x4*)(P + 16384 + e4 * 4);
    f32x4 s2 = *(const f32x4*)(P + 32768 + e4 * 4);
    f32x4 s3 = *(const f32x4*)(P + 49152 + e4 * 4);
    s += s1; s += s2; s += s3;
    if (kv == 0) {
      bf16x4 v;
#pragma unroll
      for (int r = 0; r < 4; ++r) v[r] = (bf16_t)s[r];
      *(bf16x4*)(Kp + (size_t)bh * 16384 + e4 * 4) = v;
    } else {
      int lk = (e4 * 4) >> 6, hd = (e4 * 4) & 63;
      bf16_t* d = VpT + (size_t)bh * 16384 + lk;
#pragma unroll
      for (int r = 0; r < 4; ++r) d[(size_t)(hd + r) * 256] = (bf16_t)s[r];
    }
  }
}

// ---------------- fused attention: scores -> softmax -> PV ----------------
// Grid (S/64, B*H), 256 threads (4 waves x 16 Q-rows each).
// LDS reused 3x: Kp ([256][64] 128B-row swizzled) -> P (xor) -> Vp ([64][256] swizzled).
__global__ __launch_bounds__(256) void attn_kernel(
    const bf16_t* __restrict__ Q, const bf16_t* __restrict__ Kp, const bf16_t* __restrict__ VpT,
    bf16_t* __restrict__ Xo) {
  int tid = threadIdx.x, lane = tid & 63, wv = tid >> 6;
  int q = lane >> 4, m_in = lane & 15;
  int s0 = blockIdx.x * 64;
  int bh = blockIdx.y;
  int b = bh >> 4, h = bh & 15;
  const bf16_t* Qb = Q + ((size_t)bh * 4096 + s0 + wv * 16) * 64;
  const bf16_t* Kpb = Kp + (size_t)bh * 16384;
  const bf16_t* Vb = VpT + (size_t)bh * 16384;
  __shared__ __align__(16) bf16_t buf[16384];  // 32KB, reused Kp -> P -> Vp

  // stage Kp [256][64]: 128B rows, chunk cc holds source chunk cc^(row&7)
#pragma unroll
  for (int it = 0; it < 8; ++it) {
    int l = it * 256 + tid;
    int row = l >> 3, cc = (l & 7) ^ (row & 7);
    const bf16_t* g = Kpb + row * 64 + cc * 8;
    __builtin_amdgcn_global_load_lds(TO_GLB(g), TO_LDS(buf + (it * 256 + wv * 64) * 8), 16, 0, 0);
  }
  bf16x8 aq[2];
#pragma unroll
  for (int ks = 0; ks < 2; ++ks) aq[ks] = *(const bf16x8*)(Qb + (size_t)m_in * 64 + ks * 32 + q * 8);
  __syncthreads();  // B0: Kp staged

  f32x4 sc[16];
  f32x4 z = {0.f, 0.f, 0.f, 0.f};
#pragma unroll
  for (int nt = 0; nt < 16; ++nt) sc[nt] = z;
#pragma unroll
  for (int nt = 0; nt < 16; ++nt)
#pragma unroll
    for (int ks = 0; ks < 2; ++ks) {
      int nb = nt * 16 + m_in, qq = ks * 4 + q;
      bf16x8 kb = *(const bf16x8*)(buf + nb * 64 + ((qq ^ (nb & 7)) * 8));
      sc[nt] = __builtin_amdgcn_mfma_f32_16x16x32_bf16(aq[ks], kb, sc[nt], 0, 0, 0);
    }

  float mx[4], sm[4];
#pragma unroll
  for (int r = 0; r < 4; ++r) mx[r] = -1e30f;
#pragma unroll
  for (int nt = 0; nt < 16; ++nt)
#pragma unroll
    for (int r = 0; r < 4; ++r) {
      float t = sc[nt][r] * 0.125f;  // 1/sqrt(HD)
      sc[nt][r] = t;
      mx[r] = fmaxf(mx[r], t);
    }
#pragma unroll
  for (int off = 1; off < 16; off <<= 1)
#pragma unroll
    for (int r = 0; r < 4; ++r) mx[r] = fmaxf(mx[r], __shfl_xor(mx[r], off));
#pragma unroll
  for (int r = 0; r < 4; ++r) sm[r] = 0.f;
#pragma unroll
  for (int nt = 0; nt < 16; ++nt)
#pragma unroll
    for (int r = 0; r < 4; ++r) {
      float e = __expf(sc[nt][r] - mx[r]);
      sc[nt][r] = e;
      sm[r] += e;
    }
#pragma unroll
  for (int off = 1; off < 16; off <<= 1)
#pragma unroll
    for (int r = 0; r < 4; ++r) sm[r] += __shfl_xor(sm[r], off);
  float inv[4];
#pragma unroll
  for (int r = 0; r < 4; ++r) inv[r] = 1.0f / sm[r];

  __syncthreads();  // B1: all waves done reading Kp

  bf16_t* Pw = buf + wv * 4096;
#pragma unroll
  for (int nt = 0; nt < 16; ++nt) {
    int cw = nt * 2 + (m_in >> 3);
#pragma unroll
    for (int r = 0; r < 4; ++r) {
      int rp = q * 4 + r;
      int sw = (((cw ^ (rp & 7)) << 3) | (m_in & 7));
      Pw[rp * 256 + sw] = (bf16_t)(sc[nt][r] * inv[r]);
    }
  }
  bf16x8 pa[8];
#pragma unroll
  for (int ks = 0; ks < 8; ++ks) {
    int c = ks * 4 + q;
    pa[ks] = *(const bf16x8*)(Pw + m_in * 256 + ((c ^ (m_in & 7)) << 3));
  }
  __syncthreads();  // B2: all waves hold pa

  // stage Vp [64][256]: 512B rows; position cc holds source chunk with low3 ^= row&7
#pragma unroll
  for (int it = 0; it < 8; ++it) {
    int l = it * 256 + tid;
    int row = l >> 5, cc = l & 31;
    int src_cc = (cc & 24) | ((cc ^ row) & 7);
    const bf16_t* g = Vb + row * 256 + src_cc * 8;
    __builtin_amdgcn_global_load_lds(TO_GLB(g), TO_LDS(buf + (it * 256 + wv * 64) * 8), 16, 0, 0);
  }
  __syncthreads();  // B3: Vp staged

  f32x4 o[4];
#pragma unroll
  for (int nt = 0; nt < 4; ++nt) o[nt] = z;
#pragma unroll
  for (int nt = 0; nt < 4; ++nt)
#pragma unroll
    for (int ks = 0; ks < 8; ++ks) {
      int nb = nt * 16 + m_in, qq = ks * 4 + q;
      int p = (qq & 24) | ((qq ^ nb) & 7);
      bf16x8 vb = *(const bf16x8*)(buf + nb * 256 + p * 8);
      o[nt] = __builtin_amdgcn_mfma_f32_16x16x32_bf16(pa[ks], vb, o[nt], 0, 0, 0);
    }

#pragma unroll
  for (int nt = 0; nt < 4; ++nt)
#pragma unroll
    for (int r = 0; r < 4; ++r)
      Xo[((size_t)b * 4096 + s0 + wv * 16 + q * 4 + r) * 1024 + h * 64 + nt * 16 + m_in] =
          (bf16_t)o[nt][r];
}

extern "C" void kernel_launch(void* const* d_in, const int* in_sizes, int n_in,
                              void* d_out, int out_size, void* d_ws, size_t ws_size,
                              hipStream_t stream) {
  const float* X = (const float*)d_in[0];
  const float* mask = (const float*)d_in[1];
  const float* Wq = (const float*)d_in[2];
  const float* bq = (const float*)d_in[3];
  const float* Wk = (const float*)d_in[4];
  const float* bk = (const float*)d_in[5];
  const float* Wv = (const float*)d_in[6];
  const float* bv = (const float*)d_in[7];
  const float* E = (const float*)d_in[8];
  const float* Wo = (const float*)d_in[9];
  const float* bo = (const float*)d_in[10];
  float* out = (float*)d_out;

  char* ws = (char*)d_ws;
  const size_t SZ = 33554432;  // 32 MB
  bf16_t* Xb = (bf16_t*)(ws);                 // Xb -> gemm2 partials (fp32) -> Xo
  float* Pp = (float*)(ws);                   // 32 MB fp32 partials (alias, Xb dead then)
  bf16_t* Eb = (bf16_t*)(ws + SZ);
  bf16_t* Qb = (bf16_t*)(ws + 2 * SZ);
  bf16_t* KT = (bf16_t*)(ws + 3 * SZ);        // (B,H,HD,S) masked
  bf16_t* VT = (bf16_t*)(ws + 4 * SZ);        // (B,H,HD,S) masked
  bf16_t* Kp = (bf16_t*)(ws + 5 * SZ);                 // (B,H,LK,HD)
  bf16_t* VpT = (bf16_t*)(ws + 5 * SZ + 8388608);      // (B,H,HD,LK)
  bf16_t* WqkvT = (bf16_t*)(ws + 5 * SZ + 2 * 8388608);           // (3072,1024)
  bf16_t* WoT = (bf16_t*)(ws + 5 * SZ + 2 * 8388608 + 6291456);   // (1024,1024)
  bf16_t* Xo = Xb;

  cast2_bf16_kernel<<<32768, 256, 0, stream>>>(X, Xb, E, Eb, 4194304);
  transpose_cast4<<<dim3(16, 16, 4), 256, 0, stream>>>(
      Wq, Wk, Wv, Wo, WqkvT, WqkvT + 1048576, WqkvT + 2097152, WoT);

  // QKV projection: M=16384, N=3072 -> 768 blocks, x-fastest (bm inner)
  gemm_bt_8ph<<<768, 512, 0, stream>>>(Xb, WqkvT, 1024, 0, bq, bk, bv, mask,
                                       Qb, KT, VT, nullptr, nullptr);
  gemm2_kernel<<<dim3(2, 64, 8), 512, 0, stream>>>(Eb, KT, VT, Pp);
  gemm2_reduce<<<dim3(64, 2), 256, 0, stream>>>(Pp, Kp, VpT);
  attn_kernel<<<dim3(64, 64), 256, 0, stream>>>(Qb, Kp, VpT, Xo);
  // Output projection: M=16384, N=1024 -> 256 blocks
  gemm_bt_8ph<<<256, 512, 0, stream>>>(Xo, WoT, 1024, 1, nullptr, nullptr, nullptr,
                                       nullptr, nullptr, nullptr, nullptr, bo, out);
}

// Round 4
// 429.177 us; speedup vs baseline: 1.1442x; 1.1023x over previous
//
#include <hip/hip_runtime.h>
#include <hip/hip_bf16.h>
#include <stdint.h>

// Problem constants: B=4, S=4096, D=1024, H=16, HD=64, LK=256
typedef __bf16 bf16_t;
typedef __attribute__((ext_vector_type(8))) __bf16 bf16x8;
typedef __attribute__((ext_vector_type(4))) __bf16 bf16x4;
typedef __attribute__((ext_vector_type(4))) float f32x4;

#define TO_GLB(p) ((const __attribute__((address_space(1))) void*)(p))
#define TO_LDS(p) ((__attribute__((address_space(3))) void*)(p))

// ---------------- cast fp32 -> bf16, two tensors in one launch ----------------
__global__ __launch_bounds__(256) void cast2_bf16_kernel(const float* __restrict__ a,
                                                         bf16_t* __restrict__ da,
                                                         const float* __restrict__ b,
                                                         bf16_t* __restrict__ db, int n4) {
  int i = blockIdx.x * 256 + threadIdx.x;
  const float* s = (i < n4) ? a : b;
  bf16_t* d = (i < n4) ? da : db;
  int j = (i < n4) ? i : i - n4;
  float4 v = ((const float4*)s)[j];
  bf16x4 o;
  o[0] = (bf16_t)v.x; o[1] = (bf16_t)v.y; o[2] = (bf16_t)v.z; o[3] = (bf16_t)v.w;
  ((bf16x4*)d)[j] = o;
}

// ---------------- transpose-cast 4 square matrices (1024x1024) in one launch ----------------
__global__ __launch_bounds__(256) void transpose_cast4(
    const float* __restrict__ W0, const float* __restrict__ W1, const float* __restrict__ W2,
    const float* __restrict__ W3, bf16_t* __restrict__ o0, bf16_t* __restrict__ o1,
    bf16_t* __restrict__ o2, bf16_t* __restrict__ o3) {
  const int RC = 1024;
  __shared__ bf16_t tile[64][72];
  int z = blockIdx.z;
  const float* W = (z == 0) ? W0 : (z == 1) ? W1 : (z == 2) ? W2 : W3;
  bf16_t* out = (z == 0) ? o0 : (z == 1) ? o1 : (z == 2) ? o2 : o3;
  int r0 = blockIdx.y * 64, c0 = blockIdx.x * 64;
  int tid = threadIdx.x;
#pragma unroll
  for (int p = 0; p < 4; ++p) {
    int r = p * 16 + (tid >> 4);
    int c = (tid & 15) * 4;
    float4 v = *(const float4*)(W + (size_t)(r0 + r) * RC + c0 + c);
    tile[r][c + 0] = (bf16_t)v.x; tile[r][c + 1] = (bf16_t)v.y;
    tile[r][c + 2] = (bf16_t)v.z; tile[r][c + 3] = (bf16_t)v.w;
  }
  __syncthreads();
#pragma unroll
  for (int p = 0; p < 4; ++p) {
    int c = p * 16 + (tid >> 4);
    int r = (tid & 15) * 4;
    bf16x4 o;
    o[0] = tile[r + 0][c]; o[1] = tile[r + 1][c];
    o[2] = tile[r + 2][c]; o[3] = tile[r + 3][c];
    *(bf16x4*)(out + (size_t)(c0 + c) * RC + r0 + r) = o;
  }
}

// ---------------- 256x256xBK64 bf16 GEMM, C = A @ B^T, 8-phase counted-vmcnt ----------------
// Core schedule identical to round 3. New: mode-0 epilogue bounces the 256x256 output
// tile through the (dead) 128KiB LDS so all global stores are coalesced 16B/lane:
// KT/VT rows become 512B-contiguous runs, Q rows 128B token-rows. Kills the 2x
// partial-line write amplification (WRITE_SIZE 200MB -> ~105MB).

#define AS_(s) (GemmLds + (s) * 16384)
#define BS_(s) (GemmLds + 32768 + (s) * 16384)

#define STAGE_A(s, h, k0v)                                                                   \
  do {                                                                                       \
    _Pragma("unroll") for (int it_ = 0; it_ < 2; ++it_) {                                    \
      int brow_ = it_ * 128 + (h) * 64 + (wv << 3);                                          \
      int row_ = brow_ + (lane >> 3);                                                        \
      int cc_ = (lane & 7) ^ (lane >> 3);                                                    \
      const bf16_t* ga_ = Ab + (size_t)row_ * K + (k0v) + cc_ * 8;                           \
      __builtin_amdgcn_global_load_lds(TO_GLB(ga_), TO_LDS(AS_(s) + brow_ * 64), 16, 0, 0);  \
    }                                                                                        \
  } while (0)

// B stage-half h covers rows {g*64 + h*32 .. +31, g=0..3} (matches n-quadrant deadness)
#define STAGE_B(s, h, k0v)                                                                   \
  do {                                                                                       \
    _Pragma("unroll") for (int it_ = 0; it_ < 2; ++it_) {                                    \
      int brow_ = (it_ * 2 + (wv >> 2)) * 64 + (h) * 32 + ((wv & 3) << 3);                   \
      int row_ = brow_ + (lane >> 3);                                                        \
      int cc_ = (lane & 7) ^ (lane >> 3);                                                    \
      const bf16_t* gb_ = Bb + (size_t)row_ * K + (k0v) + cc_ * 8;                           \
      __builtin_amdgcn_global_load_lds(TO_GLB(gb_), TO_LDS(BS_(s) + brow_ * 64), 16, 0, 0);  \
    }                                                                                        \
  } while (0)

#define VM4 asm volatile("s_waitcnt vmcnt(4)" ::: "memory")
#define BARRIER __builtin_amdgcn_s_barrier()
#define LGKM0 asm volatile("s_waitcnt lgkmcnt(0)" ::: "memory")

#define LOAD_AF(s, mh)                                                                       \
  do {                                                                                       \
    _Pragma("unroll") for (int kk_ = 0; kk_ < 2; ++kk_)                                      \
        _Pragma("unroll") for (int t_ = 0; t_ < 4; ++t_) {                                   \
      int ra_ = wm * 128 + (mh) * 64 + t_ * 16 + m_in;                                       \
      af[kk_][t_] = *(const bf16x8*)(AS_(s) + ra_ * 64 + (((kk_ * 4 + q) ^ (ra_ & 7)) * 8)); \
    }                                                                                        \
  } while (0)

#define LOAD_BF(s, nh, dst)                                                                  \
  do {                                                                                       \
    _Pragma("unroll") for (int kk_ = 0; kk_ < 2; ++kk_)                                      \
        _Pragma("unroll") for (int n_ = 0; n_ < 2; ++n_) {                                   \
      int rb_ = wn * 64 + (nh) * 32 + n_ * 16 + m_in;                                        \
      dst[kk_][n_] = *(const bf16x8*)(BS_(s) + rb_ * 64 + (((kk_ * 4 + q) ^ (rb_ & 7)) * 8)); \
    }                                                                                        \
  } while (0)

#define MFMA_Q(mh, nh, bfr)                                                                  \
  do {                                                                                       \
    __builtin_amdgcn_s_setprio(1);                                                           \
    _Pragma("unroll") for (int kk_ = 0; kk_ < 2; ++kk_)                                      \
        _Pragma("unroll") for (int t_ = 0; t_ < 4; ++t_)                                     \
            _Pragma("unroll") for (int n_ = 0; n_ < 2; ++n_)                                 \
                acc[(mh) * 4 + t_][(nh) * 2 + n_] = __builtin_amdgcn_mfma_f32_16x16x32_bf16( \
                    af[kk_][t_], bfr[kk_][n_], acc[(mh) * 4 + t_][(nh) * 2 + n_], 0, 0, 0);  \
    __builtin_amdgcn_s_setprio(0);                                                           \
  } while (0)

// One K-tile = 4 phases. ds_reads per phase: 12 / 4 / 8 / 0.
#define KTILE(s, ST1, ST2, ST3, ST4)                                                         \
  do {                                                                                       \
    LOAD_AF(s, 0); LOAD_BF(s, 0, bf0);                                                       \
    ST1; BARRIER; LGKM0; MFMA_Q(0, 0, bf0); BARRIER;                                         \
    LOAD_BF(s, 1, bf1);                                                                      \
    ST2; BARRIER; LGKM0; MFMA_Q(0, 1, bf1); BARRIER;                                         \
    LOAD_AF(s, 1);                                                                           \
    ST3; BARRIER; LGKM0; MFMA_Q(1, 0, bf0); BARRIER;                                         \
    ST4; VM4; BARRIER; MFMA_Q(1, 1, bf1); BARRIER;                                           \
  } while (0)

__global__ __launch_bounds__(512, 2) void gemm_bt_8ph(
    const bf16_t* __restrict__ A, const bf16_t* __restrict__ B, int K, int mode,
    const float* __restrict__ bq, const float* __restrict__ bk, const float* __restrict__ bv,
    const float* __restrict__ mask,
    bf16_t* __restrict__ Q, bf16_t* __restrict__ KT, bf16_t* __restrict__ VT,
    const float* __restrict__ bo, float* __restrict__ out) {
  int tid = threadIdx.x;
  int lane = tid & 63, wv = tid >> 6;  // 8 waves
  int wm = wv >> 2, wn = wv & 3;       // 2m x 4n
  int q = lane >> 4, m_in = lane & 15;
  int bid = blockIdx.x;
  int bm = bid & 63, bn = bid >> 6;  // x-fastest: XCD c holds bm == c (mod 8), L2-stable
  size_t m0 = (size_t)bm * 256;
  size_t n0 = (size_t)bn * 256;
  const bf16_t* Ab = A + m0 * K;
  const bf16_t* Bb = B + n0 * K;
  __shared__ __align__(16) bf16_t GemmLds[65536];  // 128KB: K-loop slots, then epilogue bounce

  f32x4 acc[8][4];
  bf16x8 af[2][4], bf0[2][2], bf1[2][2];
  f32x4 z = {0.f, 0.f, 0.f, 0.f};
#pragma unroll
  for (int mt = 0; mt < 8; ++mt)
#pragma unroll
    for (int nt = 0; nt < 4; ++nt) acc[mt][nt] = z;

  int NT = K >> 6;   // 16 K-tiles
  int NI = NT >> 1;  // 8 iterations, 2 tiles each

  // Prologue: tile0 all 4 halves into slot0; tile1 halves A0,B0 into slot1.
  STAGE_A(0, 0, 0); STAGE_B(0, 0, 0); STAGE_A(0, 1, 0); STAGE_B(0, 1, 0);
  STAGE_A(1, 0, 64); STAGE_B(1, 0, 64);
  asm volatile("s_waitcnt vmcnt(4)" ::: "memory");  // tile0 landed; tile1 A0,B0 in flight
  __builtin_amdgcn_s_barrier();

  for (int i = 0; i < NI; ++i) {
    int kt = 2 * i;
    int k1 = (kt + 1) * 64;
    int k2 = (kt + 2 < NT) ? (kt + 2) * 64 : 0;  // clamped: garbage staged, never read
    int k3 = (kt + 3 < NT) ? (kt + 3) * 64 : 0;
    KTILE(0, STAGE_A(1, 1, k1), STAGE_B(1, 1, k1), STAGE_A(0, 0, k2), STAGE_B(0, 0, k2));
    KTILE(1, STAGE_A(0, 1, k2), STAGE_B(0, 1, k2), STAGE_A(1, 0, k3), STAGE_B(1, 0, k3));
  }
  // Drain trailing garbage prefetches before LDS reuse / exit.
  asm volatile("s_waitcnt vmcnt(0)" ::: "memory");

  if (mode == 0) {
    __syncthreads();  // ALL waves drained: garbage prefetches target slots we now reuse
    int proj = (int)(n0 >> 10);
    int b = (int)(m0 >> 12), st0 = (int)(m0 & 4095);
    int nb10 = (int)(n0 & 1023);
    if (proj == 0) {
      // LDS bounce [token][n], 16B-chunk XOR swizzle on n-chunks
#pragma unroll
      for (int mt = 0; mt < 8; ++mt) {
#pragma unroll
        for (int nt = 0; nt < 4; ++nt) {
          int n = wn * 64 + nt * 16 + m_in;
          float bias = bq[nb10 + n];
#pragma unroll
          for (int r = 0; r < 4; ++r) {
            int tl = wm * 128 + mt * 16 + q * 4 + r;
            GemmLds[tl * 256 + ((((n >> 3) ^ (tl & 31)) << 3) | (n & 7))] =
                (bf16_t)(acc[mt][nt][r] + bias);
          }
        }
      }
      __syncthreads();
      int hb = (int)(n0 >> 6);
#pragma unroll
      for (int it = 0; it < 16; ++it) {
        int cid = it * 512 + tid;
        int tl = cid >> 5, c = cid & 31;
        bf16x8 v = *(const bf16x8*)(GemmLds + tl * 256 + ((c ^ (tl & 31)) << 3));
        int h = hb + (c >> 3);
        *(bf16x8*)(Q + ((size_t)(b * 16 + h) * 4096 + st0 + tl) * 64 + (c & 7) * 8) = v;
      }
    } else {
      bf16_t* dstb = (proj == 1) ? KT : VT;
      const float* bp = (proj == 1) ? bk : bv;
      // LDS bounce [n][token], 16B-chunk XOR swizzle on token-chunks
#pragma unroll
      for (int mt = 0; mt < 8; ++mt) {
        int mb = wm * 128 + mt * 16 + q * 4;
        float mk[4];
#pragma unroll
        for (int r = 0; r < 4; ++r) mk[r] = mask[b * 4096 + st0 + mb + r];
#pragma unroll
        for (int nt = 0; nt < 4; ++nt) {
          int n = wn * 64 + nt * 16 + m_in;
          float bias = bp[nb10 + n];
#pragma unroll
          for (int r = 0; r < 4; ++r) {
            int tl = mb + r;
            GemmLds[n * 256 + ((((tl >> 3) ^ (n & 31)) << 3) | (tl & 7))] =
                (bf16_t)((acc[mt][nt][r] + bias) * mk[r]);
          }
        }
      }
      __syncthreads();
#pragma unroll
      for (int it = 0; it < 16; ++it) {
        int cid = it * 512 + tid;
        int nl = cid >> 5, c = cid & 31;
        bf16x8 v = *(const bf16x8*)(GemmLds + nl * 256 + ((c ^ (nl & 31)) << 3));
        int c10 = nb10 + nl, h = c10 >> 6, hd = c10 & 63;
        *(bf16x8*)(dstb + ((size_t)(b * 16 + h) * 64 + hd) * 4096 + st0 + c * 8) = v;
      }
    }
  } else {
#pragma unroll
    for (int mt = 0; mt < 8; ++mt) {
      int t = (int)m0 + wm * 128 + mt * 16 + q * 4;
#pragma unroll
      for (int nt = 0; nt < 4; ++nt) {
        int nG = (int)n0 + wn * 64 + nt * 16 + m_in;
        float bias = bo[nG];
#pragma unroll
        for (int r = 0; r < 4; ++r) out[(size_t)(t + r) * 1024 + nG] = acc[mt][nt][r] + bias;
      }
    }
  }
}

// ---------------- GEMM2 split-K, K/V fused: partials = E_h @ (K chunk)^T and @ (V chunk)^T ----
// Grid (2 mt, 64 bh, 2 kc), 512 threads, BK=128, K-span 2048 per block.
// E staged ONCE per block and reused for both K and V MFMAs (E dup 8x -> 2x).
__global__ __launch_bounds__(512) void gemm2_kernel(
    const bf16_t* __restrict__ E, const bf16_t* __restrict__ KT, const bf16_t* __restrict__ VT,
    float* __restrict__ Pp) {
  int tid = threadIdx.x, lane = tid & 63, wv = tid >> 6;  // 8 waves
  int wm = wv >> 1, wn = wv & 1;
  int q = lane >> 4, m_in = lane & 15;
  int mt0 = blockIdx.x;
  int bh = blockIdx.y;
  int kc = blockIdx.z;
  int h = bh & 15;
  const bf16_t* Ab = E + (size_t)h * 256 * 4096 + (size_t)mt0 * 128 * 4096 + (size_t)kc * 2048;
  const bf16_t* BbK = KT + (size_t)bh * 64 * 4096 + (size_t)kc * 2048;
  const bf16_t* BbV = VT + (size_t)bh * 64 * 4096 + (size_t)kc * 2048;
  __shared__ __align__(16) bf16_t As[2 * 128 * 64];   // 32KB, [kkblk][row][64]
  __shared__ __align__(16) bf16_t BsK[2 * 64 * 64];   // 16KB
  __shared__ __align__(16) bf16_t BsV[2 * 64 * 64];   // 16KB

  f32x4 accK[2][2], accV[2][2];
  f32x4 z = {0.f, 0.f, 0.f, 0.f};
#pragma unroll
  for (int mt = 0; mt < 2; ++mt)
#pragma unroll
    for (int nt = 0; nt < 2; ++nt) { accK[mt][nt] = z; accV[mt][nt] = z; }

  for (int k0 = 0; k0 < 2048; k0 += 128) {
#pragma unroll
    for (int it = 0; it < 4; ++it) {  // As: 2048 chunks of 16B
      int l = it * 512 + tid;
      int kkb = l >> 10, row = (l >> 3) & 127, cc = (l & 7) ^ (row & 7);
      const bf16_t* ga = Ab + (size_t)row * 4096 + k0 + kkb * 64 + cc * 8;
      __builtin_amdgcn_global_load_lds(TO_GLB(ga), TO_LDS(As + (it * 512 + wv * 64) * 8), 16, 0, 0);
    }
#pragma unroll
    for (int it = 0; it < 2; ++it) {  // BsK: 1024 chunks
      int l = it * 512 + tid;
      int kkb = l >> 9, row = (l >> 3) & 63, cc = (l & 7) ^ (row & 7);
      const bf16_t* gb = BbK + (size_t)row * 4096 + k0 + kkb * 64 + cc * 8;
      __builtin_amdgcn_global_load_lds(TO_GLB(gb), TO_LDS(BsK + (it * 512 + wv * 64) * 8), 16, 0, 0);
    }
#pragma unroll
    for (int it = 0; it < 2; ++it) {  // BsV: 1024 chunks
      int l = it * 512 + tid;
      int kkb = l >> 9, row = (l >> 3) & 63, cc = (l & 7) ^ (row & 7);
      const bf16_t* gb = BbV + (size_t)row * 4096 + k0 + kkb * 64 + cc * 8;
      __builtin_amdgcn_global_load_lds(TO_GLB(gb), TO_LDS(BsV + (it * 512 + wv * 64) * 8), 16, 0, 0);
    }
    __syncthreads();
#pragma unroll
    for (int kk4 = 0; kk4 < 4; ++kk4) {
      int kkb = kk4 >> 1, qq = (kk4 & 1) * 4 + q;
      bf16x8 af[2], bK[2], bV[2];
#pragma unroll
      for (int mt = 0; mt < 2; ++mt) {
        int ra = wm * 32 + mt * 16 + m_in;
        af[mt] = *(const bf16x8*)(As + kkb * 8192 + ra * 64 + ((qq ^ (ra & 7)) * 8));
      }
#pragma unroll
      for (int nt = 0; nt < 2; ++nt) {
        int rb = wn * 32 + nt * 16 + m_in;
        bK[nt] = *(const bf16x8*)(BsK + kkb * 4096 + rb * 64 + ((qq ^ (rb & 7)) * 8));
        bV[nt] = *(const bf16x8*)(BsV + kkb * 4096 + rb * 64 + ((qq ^ (rb & 7)) * 8));
      }
#pragma unroll
      for (int mt = 0; mt < 2; ++mt)
#pragma unroll
        for (int nt = 0; nt < 2; ++nt) {
          accK[mt][nt] = __builtin_amdgcn_mfma_f32_16x16x32_bf16(af[mt], bK[nt], accK[mt][nt], 0, 0, 0);
          accV[mt][nt] = __builtin_amdgcn_mfma_f32_16x16x32_bf16(af[mt], bV[nt], accV[mt][nt], 0, 0, 0);
        }
    }
    __syncthreads();
  }

  float* PK = Pp + ((size_t)(bh * 2 + 0) * 2 + kc) * 16384;
  float* PV = Pp + ((size_t)(bh * 2 + 1) * 2 + kc) * 16384;
#pragma unroll
  for (int mt = 0; mt < 2; ++mt) {
    int lk = mt0 * 128 + wm * 32 + mt * 16 + q * 4;
#pragma unroll
    for (int nt = 0; nt < 2; ++nt) {
      int hd = wn * 32 + nt * 16 + m_in;
#pragma unroll
      for (int r = 0; r < 4; ++r) {
        PK[(size_t)(lk + r) * 64 + hd] = accK[mt][nt][r];
        PV[(size_t)(lk + r) * 64 + hd] = accV[mt][nt][r];
      }
    }
  }
}

// ---------------- reduce 2 split-K partials -> Kp bf16 [lk][hd], VpT bf16 [hd][lk] ----------------
// VpT path transposes through swizzled LDS so global writes are 512B-contiguous rows.
__global__ __launch_bounds__(256) void gemm2_reduce(const float* __restrict__ Pp,
                                                    bf16_t* __restrict__ Kp,
                                                    bf16_t* __restrict__ VpT) {
  int bh = blockIdx.x, kv = blockIdx.y;
  int tid = threadIdx.x;
  const float* P = Pp + ((size_t)(bh * 2 + kv) * 2) * 16384;
  if (kv == 0) {
#pragma unroll
    for (int it = 0; it < 16; ++it) {
      int e4 = it * 256 + tid;
      f32x4 s = *(const f32x4*)(P + e4 * 4);
      f32x4 s1 = *(const f32x4*)(P + 16384 + e4 * 4);
      s += s1;
      bf16x4 v;
#pragma unroll
      for (int r = 0; r < 4; ++r) v[r] = (bf16_t)s[r];
      *(bf16x4*)(Kp + (size_t)bh * 16384 + e4 * 4) = v;
    }
  } else {
    __shared__ __align__(16) bf16_t T[16384];  // 32KB [hd][lk], chunk-XOR swizzled
#pragma unroll
    for (int it = 0; it < 16; ++it) {
      int e4 = it * 256 + tid;
      f32x4 s = *(const f32x4*)(P + e4 * 4);
      f32x4 s1 = *(const f32x4*)(P + 16384 + e4 * 4);
      s += s1;
      int lk = (e4 * 4) >> 6, hd0 = (e4 * 4) & 63;
#pragma unroll
      for (int r = 0; r < 4; ++r) {
        int hd = hd0 + r;
        T[hd * 256 + ((((lk >> 3) ^ (hd & 31)) << 3) | (lk & 7))] = (bf16_t)s[r];
      }
    }
    __syncthreads();
#pragma unroll
    for (int it = 0; it < 8; ++it) {
      int cid = it * 256 + tid;
      int hd = cid >> 5, c = cid & 31;
      bf16x8 v = *(const bf16x8*)(T + hd * 256 + ((c ^ (hd & 31)) << 3));
      *(bf16x8*)(VpT + (size_t)bh * 16384 + hd * 256 + c * 8) = v;
    }
  }
}

// ---------------- fused attention: scores -> softmax -> PV ----------------
// Grid (S/64, B*H), 256 threads (4 waves x 16 Q-rows each).
// LDS reused 3x: Kp ([256][64] 128B-row swizzled) -> P (xor) -> Vp ([64][256] swizzled).
__global__ __launch_bounds__(256) void attn_kernel(
    const bf16_t* __restrict__ Q, const bf16_t* __restrict__ Kp, const bf16_t* __restrict__ VpT,
    bf16_t* __restrict__ Xo) {
  int tid = threadIdx.x, lane = tid & 63, wv = tid >> 6;
  int q = lane >> 4, m_in = lane & 15;
  int s0 = blockIdx.x * 64;
  int bh = blockIdx.y;
  int b = bh >> 4, h = bh & 15;
  const bf16_t* Qb = Q + ((size_t)bh * 4096 + s0 + wv * 16) * 64;
  const bf16_t* Kpb = Kp + (size_t)bh * 16384;
  const bf16_t* Vb = VpT + (size_t)bh * 16384;
  __shared__ __align__(16) bf16_t buf[16384];  // 32KB, reused Kp -> P -> Vp

  // stage Kp [256][64]: 128B rows, chunk cc holds source chunk cc^(row&7)
#pragma unroll
  for (int it = 0; it < 8; ++it) {
    int l = it * 256 + tid;
    int row = l >> 3, cc = (l & 7) ^ (row & 7);
    const bf16_t* g = Kpb + row * 64 + cc * 8;
    __builtin_amdgcn_global_load_lds(TO_GLB(g), TO_LDS(buf + (it * 256 + wv * 64) * 8), 16, 0, 0);
  }
  bf16x8 aq[2];
#pragma unroll
  for (int ks = 0; ks < 2; ++ks) aq[ks] = *(const bf16x8*)(Qb + (size_t)m_in * 64 + ks * 32 + q * 8);
  __syncthreads();  // B0: Kp staged

  f32x4 sc[16];
  f32x4 z = {0.f, 0.f, 0.f, 0.f};
#pragma unroll
  for (int nt = 0; nt < 16; ++nt) sc[nt] = z;
#pragma unroll
  for (int nt = 0; nt < 16; ++nt)
#pragma unroll
    for (int ks = 0; ks < 2; ++ks) {
      int nb = nt * 16 + m_in, qq = ks * 4 + q;
      bf16x8 kb = *(const bf16x8*)(buf + nb * 64 + ((qq ^ (nb & 7)) * 8));
      sc[nt] = __builtin_amdgcn_mfma_f32_16x16x32_bf16(aq[ks], kb, sc[nt], 0, 0, 0);
    }

  float mx[4], sm[4];
#pragma unroll
  for (int r = 0; r < 4; ++r) mx[r] = -1e30f;
#pragma unroll
  for (int nt = 0; nt < 16; ++nt)
#pragma unroll
    for (int r = 0; r < 4; ++r) {
      float t = sc[nt][r] * 0.125f;  // 1/sqrt(HD)
      sc[nt][r] = t;
      mx[r] = fmaxf(mx[r], t);
    }
#pragma unroll
  for (int off = 1; off < 16; off <<= 1)
#pragma unroll
    for (int r = 0; r < 4; ++r) mx[r] = fmaxf(mx[r], __shfl_xor(mx[r], off));
#pragma unroll
  for (int r = 0; r < 4; ++r) sm[r] = 0.f;
#pragma unroll
  for (int nt = 0; nt < 16; ++nt)
#pragma unroll
    for (int r = 0; r < 4; ++r) {
      float e = __expf(sc[nt][r] - mx[r]);
      sc[nt][r] = e;
      sm[r] += e;
    }
#pragma unroll
  for (int off = 1; off < 16; off <<= 1)
#pragma unroll
    for (int r = 0; r < 4; ++r) sm[r] += __shfl_xor(sm[r], off);
  float inv[4];
#pragma unroll
  for (int r = 0; r < 4; ++r) inv[r] = 1.0f / sm[r];

  __syncthreads();  // B1: all waves done reading Kp

  bf16_t* Pw = buf + wv * 4096;
#pragma unroll
  for (int nt = 0; nt < 16; ++nt) {
    int cw = nt * 2 + (m_in >> 3);
#pragma unroll
    for (int r = 0; r < 4; ++r) {
      int rp = q * 4 + r;
      int sw = (((cw ^ (rp & 7)) << 3) | (m_in & 7));
      Pw[rp * 256 + sw] = (bf16_t)(sc[nt][r] * inv[r]);
    }
  }
  bf16x8 pa[8];
#pragma unroll
  for (int ks = 0; ks < 8; ++ks) {
    int c = ks * 4 + q;
    pa[ks] = *(const bf16x8*)(Pw + m_in * 256 + ((c ^ (m_in & 7)) << 3));
  }
  __syncthreads();  // B2: all waves hold pa

  // stage Vp [64][256]: 512B rows; position cc holds source chunk with low3 ^= row&7
#pragma unroll
  for (int it = 0; it < 8; ++it) {
    int l = it * 256 + tid;
    int row = l >> 5, cc = l & 31;
    int src_cc = (cc & 24) | ((cc ^ row) & 7);
    const bf16_t* g = Vb + row * 256 + src_cc * 8;
    __builtin_amdgcn_global_load_lds(TO_GLB(g), TO_LDS(buf + (it * 256 + wv * 64) * 8), 16, 0, 0);
  }
  __syncthreads();  // B3: Vp staged

  f32x4 o[4];
#pragma unroll
  for (int nt = 0; nt < 4; ++nt) o[nt] = z;
#pragma unroll
  for (int nt = 0; nt < 4; ++nt)
#pragma unroll
    for (int ks = 0; ks < 8; ++ks) {
      int nb = nt * 16 + m_in, qq = ks * 4 + q;
      int p = (qq & 24) | ((qq ^ nb) & 7);
      bf16x8 vb = *(const bf16x8*)(buf + nb * 256 + p * 8);
      o[nt] = __builtin_amdgcn_mfma_f32_16x16x32_bf16(pa[ks], vb, o[nt], 0, 0, 0);
    }

#pragma unroll
  for (int nt = 0; nt < 4; ++nt)
#pragma unroll
    for (int r = 0; r < 4; ++r)
      Xo[((size_t)b * 4096 + s0 + wv * 16 + q * 4 + r) * 1024 + h * 64 + nt * 16 + m_in] =
          (bf16_t)o[nt][r];
}

extern "C" void kernel_launch(void* const* d_in, const int* in_sizes, int n_in,
                              void* d_out, int out_size, void* d_ws, size_t ws_size,
                              hipStream_t stream) {
  const float* X = (const float*)d_in[0];
  const float* mask = (const float*)d_in[1];
  const float* Wq = (const float*)d_in[2];
  const float* bq = (const float*)d_in[3];
  const float* Wk = (const float*)d_in[4];
  const float* bk = (const float*)d_in[5];
  const float* Wv = (const float*)d_in[6];
  const float* bv = (const float*)d_in[7];
  const float* E = (const float*)d_in[8];
  const float* Wo = (const float*)d_in[9];
  const float* bo = (const float*)d_in[10];
  float* out = (float*)d_out;

  char* ws = (char*)d_ws;
  const size_t SZ = 33554432;  // 32 MB
  bf16_t* Xb = (bf16_t*)(ws);                 // Xb -> gemm2 partials (fp32, 16MB) -> Xo
  float* Pp = (float*)(ws);                   // fp32 partials (alias, Xb dead then)
  bf16_t* Eb = (bf16_t*)(ws + SZ);
  bf16_t* Qb = (bf16_t*)(ws + 2 * SZ);
  bf16_t* KT = (bf16_t*)(ws + 3 * SZ);        // (B,H,HD,S) masked
  bf16_t* VT = (bf16_t*)(ws + 4 * SZ);        // (B,H,HD,S) masked
  bf16_t* Kp = (bf16_t*)(ws + 5 * SZ);                 // (B,H,LK,HD)
  bf16_t* VpT = (bf16_t*)(ws + 5 * SZ + 8388608);      // (B,H,HD,LK)
  bf16_t* WqkvT = (bf16_t*)(ws + 5 * SZ + 2 * 8388608);           // (3072,1024)
  bf16_t* WoT = (bf16_t*)(ws + 5 * SZ + 2 * 8388608 + 6291456);   // (1024,1024)
  bf16_t* Xo = Xb;

  cast2_bf16_kernel<<<32768, 256, 0, stream>>>(X, Xb, E, Eb, 4194304);
  transpose_cast4<<<dim3(16, 16, 4), 256, 0, stream>>>(
      Wq, Wk, Wv, Wo, WqkvT, WqkvT + 1048576, WqkvT + 2097152, WoT);

  // QKV projection: M=16384, N=3072 -> 768 blocks, x-fastest (bm inner)
  gemm_bt_8ph<<<768, 512, 0, stream>>>(Xb, WqkvT, 1024, 0, bq, bk, bv, mask,
                                       Qb, KT, VT, nullptr, nullptr);
  // K/V-fused split-K projection onto E: 256 blocks (1/CU)
  gemm2_kernel<<<dim3(2, 64, 2), 512, 0, stream>>>(Eb, KT, VT, Pp);
  gemm2_reduce<<<dim3(64, 2), 256, 0, stream>>>(Pp, Kp, VpT);
  attn_kernel<<<dim3(64, 64), 256, 0, stream>>>(Qb, Kp, VpT, Xo);
  // Output projection: M=16384, N=1024 -> 256 blocks
  gemm_bt_8ph<<<256, 512, 0, stream>>>(Xo, WoT, 1024, 1, nullptr, nullptr, nullptr,
                                       nullptr, nullptr, nullptr, nullptr, bo, out);
}